// Round 12
// baseline (508.111 us; speedup 1.0000x reference)
//
#include <hip/hip_runtime.h>
#include <hip/hip_bf16.h>
#include <cstdint>

#define NN 12288
#define NT 192   // K tiles of 64

typedef __attribute__((ext_vector_type(8))) short bfrag8;
typedef __attribute__((ext_vector_type(4))) float f32x4;
typedef __attribute__((ext_vector_type(2))) uint32_t u32x2;
typedef __attribute__((ext_vector_type(4))) uint32_t u32x4;

__device__ __forceinline__ uint16_t f2bf_rtn(float f) {
    uint32_t u = __float_as_uint(f);
    return (uint16_t)((u + 0x7fffu + ((u >> 16) & 1u)) >> 16);
}
__device__ __forceinline__ void split_bf(float f, uint16_t& hb, uint16_t& lb) {
    uint32_t u = __float_as_uint(f);
    hb = (uint16_t)(u >> 16);
    float fr = f - __uint_as_float(u & 0xffff0000u);
    lb = f2bf_rtn(fr);
}

// Packed hi/lo split of 4 floats (v_cvt_pk_bf16_f32 via official intrinsic).
// hi = RNE bf16 pair; residual f-hi exactly representable; lo = RNE(residual).
__device__ __forceinline__ void split4_pk(const f32x4& f, u32x2& hi, u32x2& lo) {
    float2 p01; p01.x = f[0]; p01.y = f[1];
    float2 p23; p23.x = f[2]; p23.y = f[3];
    __hip_bfloat162 h01 = __float22bfloat162_rn(p01);
    __hip_bfloat162 h23 = __float22bfloat162_rn(p23);
    uint32_t uh01 = *reinterpret_cast<uint32_t*>(&h01);
    uint32_t uh23 = *reinterpret_cast<uint32_t*>(&h23);
    float2 r01, r23;
    r01.x = f[0] - __uint_as_float(uh01 << 16);
    r01.y = f[1] - __uint_as_float(uh01 & 0xffff0000u);
    r23.x = f[2] - __uint_as_float(uh23 << 16);
    r23.y = f[3] - __uint_as_float(uh23 & 0xffff0000u);
    __hip_bfloat162 l01 = __float22bfloat162_rn(r01);
    __hip_bfloat162 l23 = __float22bfloat162_rn(r23);
    hi[0] = uh01; hi[1] = uh23;
    lo[0] = *reinterpret_cast<uint32_t*>(&l01);
    lo[1] = *reinterpret_cast<uint32_t*>(&l23);
}

// ---------------------------------------------------------------------------
__global__ void wt4_kernel(const float* __restrict__ w0, const float* __restrict__ w1,
                           const float* __restrict__ w2, const float* __restrict__ w3,
                           float* __restrict__ o0, float* __restrict__ o1,
                           float* __restrict__ o2, float* __restrict__ o3) {
    const float* w; float* o;
    switch (blockIdx.y) {
        case 0: w = w0; o = o0; break;
        case 1: w = w1; o = o1; break;
        case 2: w = w2; o = o2; break;
        default: w = w3; o = o3; break;
    }
    int i = blockIdx.x * 256 + threadIdx.x;
    if (i < 192 * 64) {
        int r = i / 64, k = i % 64;
        o[k * 192 + r] = w[i];
    }
}

// ---------------------------------------------------------------------------
// B = X @ W (fp32) -> tile-contiguous packed bf16 hi/lo:
//   Bpk[(k>>6)*8192 + part*4096 + (((k>>3)&7)*64 + c)*8 + (k&7)]
__global__ void __launch_bounds__(256) xw_kernel(const float* __restrict__ X,
                                                 const float* __restrict__ W,
                                                 uint16_t* __restrict__ Bpk) {
    __shared__ __align__(16) float sW[64 * 65];
    __shared__ __align__(16) float sX[64 * 65];
    const int t = threadIdx.x;
    const int rb = blockIdx.x * 64;
    for (int i = t; i < 4096; i += 256) {
        int rr = i >> 6, cc = i & 63;
        sW[rr * 65 + cc] = W[i];
        sX[rr * 65 + cc] = X[(size_t)rb * 64 + i];
    }
    __syncthreads();
    const int r = t & 63;
    const int c0 = (t >> 6) * 16;
    float acc[16];
#pragma unroll
    for (int i = 0; i < 16; i++) acc[i] = 0.f;
    for (int k = 0; k < 64; k++) {
        float xv = sX[r * 65 + k];
#pragma unroll
        for (int i = 0; i < 16; i++) acc[i] += xv * sW[k * 65 + c0 + i];
    }
    const int j = rb + r;
    const size_t base = (size_t)(j >> 6) * 8192 + (size_t)((j >> 3) & 7) * 512 + (j & 7);
#pragma unroll
    for (int i = 0; i < 16; i++) {
        uint16_t hb, lb;
        split_bf(acc[i], hb, lb);
        size_t idx = base + (size_t)(c0 + i) * 8;
        Bpk[idx] = hb;
        Bpk[idx + 4096] = lb;
    }
}

// ---------------------------------------------------------------------------
// m = adj @ B   (bf16 hi/lo, 3-MFMA), zero-LDS / zero-barrier variant.
// grid 768 x 64 (ONE wave per block). Block owns 16 output rows x 64 cols,
// sweeps the FULL K (192 tiles): each adj row is read by exactly one wave,
// sequentially (12288 streams of 48KB) -> DRAM-friendly.
// A fragment = lane's own 8 consecutive floats (2 x dwordx4), converted
// in-register. B fragments read directly from packed Bpk (L2-resident).
// Latency: 4-deep named A ring (~HBM latency), B ping-pong (L2 latency).
struct ATile { f32x4 v[4]; };
struct BTile { bfrag8 h[2][4]; bfrag8 l[2][4]; };

__global__ void __launch_bounds__(64) spmm_kernel(
    const float* __restrict__ adj,
    const uint16_t* __restrict__ Bpk,
    float* __restrict__ mout,
    int rev) {
    const int band = blockIdx.x;          // 16-row band
    const int lane = threadIdx.x;         // 0..63
    const int kq = lane >> 4;             // 0..3
    const int colb = lane & 15;
    const float* arow = adj + (size_t)(band * 16 + colb) * NN;  // lane's A row

    f32x4 acc[4];
#pragma unroll
    for (int i = 0; i < 4; i++) {
        acc[i][0] = 0.f; acc[i][1] = 0.f; acc[i][2] = 0.f; acc[i][3] = 0.f;
    }

    auto g = [&](int t) { return rev ? (NT - 1 - t) : t; };

    auto load_A = [&](int t, ATile& A) {
        const float* p = arow + (size_t)g(t) * 64 + kq * 8;
        A.v[0] = *(const f32x4*)(p);
        A.v[1] = *(const f32x4*)(p + 4);
        A.v[2] = *(const f32x4*)(p + 32);
        A.v[3] = *(const f32x4*)(p + 36);
    };
    auto load_B = [&](int t, BTile& B) {
        const uint16_t* bp = Bpk + (size_t)g(t) * 8192;
#pragma unroll
        for (int ks = 0; ks < 2; ++ks) {
            const int bko = (ks * 4 + kq) * 512;
#pragma unroll
            for (int ct = 0; ct < 4; ++ct) {
                const int off = bko + (ct * 16 + colb) * 8;
                B.h[ks][ct] = *(const bfrag8*)(bp + off);
                B.l[ks][ct] = *(const bfrag8*)(bp + 4096 + off);
            }
        }
    };
    auto compute = [&](ATile& A, BTile& B) {
#pragma unroll
        for (int ks = 0; ks < 2; ++ks) {
            u32x2 h0, l0, h1, l1;
            split4_pk(A.v[ks * 2], h0, l0);
            split4_pk(A.v[ks * 2 + 1], h1, l1);
            u32x4 H, L;
            H[0] = h0[0]; H[1] = h0[1]; H[2] = h1[0]; H[3] = h1[1];
            L[0] = l0[0]; L[1] = l0[1]; L[2] = l1[0]; L[3] = l1[1];
            bfrag8 ah = *(bfrag8*)&H;
            bfrag8 al = *(bfrag8*)&L;
#pragma unroll
            for (int ct = 0; ct < 4; ++ct) {
                acc[ct] = __builtin_amdgcn_mfma_f32_16x16x32_bf16(ah, B.h[ks][ct], acc[ct], 0, 0, 0);
                acc[ct] = __builtin_amdgcn_mfma_f32_16x16x32_bf16(al, B.h[ks][ct], acc[ct], 0, 0, 0);
                acc[ct] = __builtin_amdgcn_mfma_f32_16x16x32_bf16(ah, B.l[ks][ct], acc[ct], 0, 0, 0);
            }
        }
    };

    ATile A0, A1, A2, A3;
    BTile B0, B1;
    load_A(0, A0); load_A(1, A1); load_A(2, A2); load_A(3, A3);
    load_B(0, B0); load_B(1, B1);

    for (int t = 0; t < NT; t += 4) {
        compute(A0, B0);
        if (t + 4 < NT) load_A(t + 4, A0);
        if (t + 2 < NT) load_B(t + 2, B0);
        compute(A1, B1);
        if (t + 5 < NT) load_A(t + 5, A1);
        if (t + 3 < NT) load_B(t + 3, B1);
        compute(A2, B0);
        if (t + 6 < NT) load_A(t + 6, A2);
        if (t + 4 < NT) load_B(t + 4, B0);
        compute(A3, B1);
        if (t + 7 < NT) load_A(t + 7, A3);
        if (t + 5 < NT) load_B(t + 5, B1);
    }

    // epilogue: C layout (m89-verified): col = lane&15, row = (lane>>4)*4 + reg
    const int orow0 = band * 16 + (lane >> 4) * 4;
#pragma unroll
    for (int ct = 0; ct < 4; ++ct) {
#pragma unroll
        for (int r = 0; r < 4; ++r) {
            mout[(size_t)(orow0 + r) * 64 + ct * 16 + colb] = acc[ct][r];
        }
    }
}

// ---------------------------------------------------------------------------
// Fused: GRUCell(m, x); relu; write fp32 output.
__global__ void __launch_bounds__(256, 4) gru_kernel(
    const float* __restrict__ m_in,
    const float* __restrict__ Xin,
    const float* __restrict__ wtih,  // [64][192]
    const float* __restrict__ wthh,  // [64][192]
    const float* __restrict__ bih,
    const float* __restrict__ bhh,
    float* __restrict__ hout) {
    __shared__ __align__(16) float sM[32 * 64];
    __shared__ __align__(16) float sX[32 * 64];
    const int t = threadIdx.x;
    const int nb = blockIdx.x * 32;
    {
        size_t g0 = (size_t)nb * 64 + (size_t)t * 8;
        const f32x4* pm = (const f32x4*)(m_in + g0);
        *(f32x4*)&sM[t * 8] = pm[0];
        *(f32x4*)&sM[t * 8 + 4] = pm[1];
        const f32x4* px = (const f32x4*)(Xin + g0);
        *(f32x4*)&sX[t * 8] = px[0];
        *(f32x4*)&sX[t * 8 + 4] = px[1];
    }
    __syncthreads();
    const int wave = t >> 6, lane = t & 63;
    const int nodebase = wave * 8;
    float a_ir[8], a_iz[8], a_in[8], a_hr[8], a_hz[8], a_hn[8];
#pragma unroll
    for (int n = 0; n < 8; n++) {
        a_ir[n] = 0.f; a_iz[n] = 0.f; a_in[n] = 0.f;
        a_hr[n] = 0.f; a_hz[n] = 0.f; a_hn[n] = 0.f;
    }
    for (int k = 0; k < 64; k++) {
        float w0 = wtih[k * 192 + lane];
        float w1 = wtih[k * 192 + 64 + lane];
        float w2 = wtih[k * 192 + 128 + lane];
        float w3 = wthh[k * 192 + lane];
        float w4 = wthh[k * 192 + 64 + lane];
        float w5 = wthh[k * 192 + 128 + lane];
#pragma unroll
        for (int n = 0; n < 8; n++) {
            float mv = sM[(nodebase + n) * 64 + k];
            float xv = sX[(nodebase + n) * 64 + k];
            a_ir[n] += w0 * mv; a_iz[n] += w1 * mv; a_in[n] += w2 * mv;
            a_hr[n] += w3 * xv; a_hz[n] += w4 * xv; a_hn[n] += w5 * xv;
        }
    }
    const float b0 = bih[lane], b1 = bih[64 + lane], b2 = bih[128 + lane];
    const float b3 = bhh[lane], b4 = bhh[64 + lane], b5 = bhh[128 + lane];
#pragma unroll
    for (int n = 0; n < 8; n++) {
        float ir = a_ir[n] + b0, iz = a_iz[n] + b1, inn = a_in[n] + b2;
        float hr = a_hr[n] + b3, hz = a_hz[n] + b4, hn = a_hn[n] + b5;
        float r = 1.f / (1.f + __expf(-(ir + hr)));
        float z = 1.f / (1.f + __expf(-(iz + hz)));
        float nt = tanhf(inn + r * hn);
        float xv = sX[(nodebase + n) * 64 + lane];
        float o = (1.f - z) * nt + z * xv;
        o = fmaxf(o, 0.f);
        size_t oi = (size_t)(nb + nodebase + n) * 64 + lane;
        hout[oi] = o;
    }
}

// ---------------------------------------------------------------------------
extern "C" void kernel_launch(void* const* d_in, const int* in_sizes, int n_in,
                              void* d_out, int out_size, void* d_ws, size_t ws_size,
                              hipStream_t stream) {
    const float* x    = (const float*)d_in[0];
    const float* adj  = (const float*)d_in[1];
    const float* W1   = (const float*)d_in[2];
    const float* wih1 = (const float*)d_in[3];
    const float* whh1 = (const float*)d_in[4];
    const float* bih1 = (const float*)d_in[5];
    const float* bhh1 = (const float*)d_in[6];
    const float* W2   = (const float*)d_in[7];
    const float* wih2 = (const float*)d_in[8];
    const float* whh2 = (const float*)d_in[9];
    const float* bih2 = (const float*)d_in[10];
    const float* bhh2 = (const float*)d_in[11];
    float* out = (float*)d_out;   // reference output dtype is float32

    char* p = (char*)d_ws;
    float* wtih1 = (float*)p; p += (size_t)192 * 64 * 4;
    float* wthh1 = (float*)p; p += (size_t)192 * 64 * 4;
    float* wtih2 = (float*)p; p += (size_t)192 * 64 * 4;
    float* wthh2 = (float*)p; p += (size_t)192 * 64 * 4;
    float* h     = (float*)p; p += (size_t)NN * 64 * 4;
    float* m     = (float*)p; p += (size_t)NN * 64 * 4;
    uint16_t* Bpk = (uint16_t*)p; p += (size_t)NN * 64 * 2 * 2;  // hi+lo packed

    wt4_kernel<<<dim3(48, 4), 256, 0, stream>>>(wih1, whh1, wih2, whh2,
                                                wtih1, wthh1, wtih2, wthh2);

    // layer 1 (forward K order)
    xw_kernel<<<192, 256, 0, stream>>>(x, W1, Bpk);
    spmm_kernel<<<768, 64, 0, stream>>>(adj, Bpk, m, 0);
    gru_kernel<<<384, 256, 0, stream>>>(m, x, wtih1, wthh1, bih1, bhh1, h);
    // layer 2 (reverse K order — boustrophedon: reuse adj tail still in L3)
    xw_kernel<<<192, 256, 0, stream>>>(h, W2, Bpk);
    spmm_kernel<<<768, 64, 0, stream>>>(adj, Bpk, m, 1);
    gru_kernel<<<384, 256, 0, stream>>>(m, h, wtih2, wthh2, bih2, bhh2, out);
}

// Round 13
// 361.459 us; speedup vs baseline: 1.4057x; 1.4057x over previous
//
#include <hip/hip_runtime.h>
#include <hip/hip_bf16.h>
#include <cstdint>

#define NN 12288

typedef __attribute__((ext_vector_type(8))) short bfrag8;
typedef __attribute__((ext_vector_type(4))) float f32x4;
typedef __attribute__((ext_vector_type(2))) uint32_t u32x2;
typedef __attribute__((ext_vector_type(4))) uint32_t u32x4;

__device__ __forceinline__ uint16_t f2bf_rtn(float f) {
    uint32_t u = __float_as_uint(f);
    return (uint16_t)((u + 0x7fffu + ((u >> 16) & 1u)) >> 16);
}
__device__ __forceinline__ void split_bf(float f, uint16_t& hb, uint16_t& lb) {
    uint32_t u = __float_as_uint(f);
    hb = (uint16_t)(u >> 16);
    float fr = f - __uint_as_float(u & 0xffff0000u);
    lb = f2bf_rtn(fr);
}

// Packed hi/lo split of 4 floats (v_cvt_pk_bf16_f32 via official intrinsic).
__device__ __forceinline__ void split4_pk(const f32x4& f, u32x2& hi, u32x2& lo) {
    float2 p01; p01.x = f[0]; p01.y = f[1];
    float2 p23; p23.x = f[2]; p23.y = f[3];
    __hip_bfloat162 h01 = __float22bfloat162_rn(p01);
    __hip_bfloat162 h23 = __float22bfloat162_rn(p23);
    uint32_t uh01 = *reinterpret_cast<uint32_t*>(&h01);
    uint32_t uh23 = *reinterpret_cast<uint32_t*>(&h23);
    float2 r01, r23;
    r01.x = f[0] - __uint_as_float(uh01 << 16);
    r01.y = f[1] - __uint_as_float(uh01 & 0xffff0000u);
    r23.x = f[2] - __uint_as_float(uh23 << 16);
    r23.y = f[3] - __uint_as_float(uh23 & 0xffff0000u);
    __hip_bfloat162 l01 = __float22bfloat162_rn(r01);
    __hip_bfloat162 l23 = __float22bfloat162_rn(r23);
    hi[0] = uh01; hi[1] = uh23;
    lo[0] = *reinterpret_cast<uint32_t*>(&l01);
    lo[1] = *reinterpret_cast<uint32_t*>(&l23);
}

// async global->LDS, 16B per lane (DMA; dest = uniform base + lane*16)
__device__ __forceinline__ void gload16(const void* g, void* l) {
    __builtin_amdgcn_global_load_lds(
        (const __attribute__((address_space(1))) uint32_t*)(uintptr_t)g,
        (__attribute__((address_space(3))) uint32_t*)(uintptr_t)l,
        16, 0, 0);
}

// Barrier that fences LDS ops only (keeps global DMA in flight).
__device__ __forceinline__ void lds_sync() {
    asm volatile("s_waitcnt lgkmcnt(0)" ::: "memory");
    __builtin_amdgcn_s_barrier();
    asm volatile("" ::: "memory");
}
// Wait for all outstanding global->LDS DMA, then barrier.
__device__ __forceinline__ void vm_sync() {
    asm volatile("s_waitcnt vmcnt(0)" ::: "memory");
    __builtin_amdgcn_s_barrier();
    asm volatile("" ::: "memory");
}

// ---------------------------------------------------------------------------
__global__ void wt4_kernel(const float* __restrict__ w0, const float* __restrict__ w1,
                           const float* __restrict__ w2, const float* __restrict__ w3,
                           float* __restrict__ o0, float* __restrict__ o1,
                           float* __restrict__ o2, float* __restrict__ o3) {
    const float* w; float* o;
    switch (blockIdx.y) {
        case 0: w = w0; o = o0; break;
        case 1: w = w1; o = o1; break;
        case 2: w = w2; o = o2; break;
        default: w = w3; o = o3; break;
    }
    int i = blockIdx.x * 256 + threadIdx.x;
    if (i < 192 * 64) {
        int r = i / 64, k = i % 64;
        o[k * 192 + r] = w[i];
    }
}

// ---------------------------------------------------------------------------
// B = X @ W (fp32) -> tile-contiguous packed bf16 hi/lo:
//   Bpk[(k>>6)*8192 + part*4096 + (((k>>3)&7)*64 + c)*8 + (k&7)]
__global__ void __launch_bounds__(256) xw_kernel(const float* __restrict__ X,
                                                 const float* __restrict__ W,
                                                 uint16_t* __restrict__ Bpk) {
    __shared__ __align__(16) float sW[64 * 65];
    __shared__ __align__(16) float sX[64 * 65];
    const int t = threadIdx.x;
    const int rb = blockIdx.x * 64;
    for (int i = t; i < 4096; i += 256) {
        int rr = i >> 6, cc = i & 63;
        sW[rr * 65 + cc] = W[i];
        sX[rr * 65 + cc] = X[(size_t)rb * 64 + i];
    }
    __syncthreads();
    const int r = t & 63;
    const int c0 = (t >> 6) * 16;
    float acc[16];
#pragma unroll
    for (int i = 0; i < 16; i++) acc[i] = 0.f;
    for (int k = 0; k < 64; k++) {
        float xv = sX[r * 65 + k];
#pragma unroll
        for (int i = 0; i < 16; i++) acc[i] += xv * sW[k * 65 + c0 + i];
    }
    const int j = rb + r;
    const size_t base = (size_t)(j >> 6) * 8192 + (size_t)((j >> 3) & 7) * 512 + (j & 7);
#pragma unroll
    for (int i = 0; i < 16; i++) {
        uint16_t hb, lb;
        split_bf(acc[i], hb, lb);
        size_t idx = base + (size_t)(c0 + i) * 8;
        Bpk[idx] = hb;
        Bpk[idx + 4096] = lb;
    }
}

// ---------------------------------------------------------------------------
// partial[kc] = adj[:, kchunk] @ B[kchunk, :]   (bf16 hi/lo, 3-MFMA)
// grid (192, KSPLIT), block 128 (2 waves). Tile: 64 rows x 64 cols x 64 k.
// A: fp32 via global_load_lds DMA (no regs, no staging VALU), double-buffered,
//    content XOR-swizzled by pre-swizzling the per-lane GLOBAL chunk address
//    (rule #21: linear dest + inverse-swz source + swz read). hi/lo split at
//    fragment-read time (same bytes: fp32 4B == hi+lo 2x2B).
// B: 16KB identity DMA copy of packed Bpk tile (L2-resident), single buffer.
// Per tile: vm_sync (A+B ready) -> issue A(t+1) -> compute -> lds_sync ->
//           issue B(t+1). LDS = 2*16K(A) + 16K(B) = 48KB -> 3 blocks/CU,
//           768-block grid exactly resident.
__global__ void __launch_bounds__(128, 2) spmm_kernel(
    const float* __restrict__ adj,
    const uint16_t* __restrict__ Bpk,
    float* __restrict__ partial,
    int ktiles, int rev) {
    __shared__ __align__(16) float sA[2][4096];     // [buf][64 rows][64 k] fp32
    __shared__ __align__(16) uint16_t sB[8192];     // hi(4096)+lo(4096)
    const int t = threadIdx.x;
    const int rb = blockIdx.x;
    const int kc = blockIdx.y;
    const int tile0 = kc * ktiles;
    const int wave = t >> 6, lane = t & 63;
    const int kq = lane >> 4;                        // 0..3
    const float* aptr = adj + (size_t)rb * 64 * NN;

    f32x4 acc[2][4];
#pragma unroll
    for (int rt = 0; rt < 2; rt++)
#pragma unroll
        for (int ct = 0; ct < 4; ct++) {
            acc[rt][ct][0] = 0.f; acc[rt][ct][1] = 0.f;
            acc[rt][ct][2] = 0.f; acc[rt][ct][3] = 0.f;
        }

    auto tid2glob = [&](int i) { return tile0 + (rev ? (ktiles - 1 - i) : i); };

    // --- A DMA: wave w stages its own rows w*32..w*32+31; 8 insts of 1KB.
    // LDS slot (rowb, c_lds=lane&15) receives global chunk c_lds ^ (rowb&7).
    const int a_rl = lane >> 4;       // row within 4-row group
    const int a_cl = lane & 15;       // LDS chunk slot
    auto issue_A = [&](int tl, int buf) {
        const float* tb = aptr + (size_t)tid2glob(tl) * 64;
#pragma unroll
        for (int i = 0; i < 8; ++i) {
            int rowb = wave * 32 + i * 4 + a_rl;
            int cg = a_cl ^ (rowb & 7);
            const float* gp = tb + (size_t)rowb * NN + cg * 4;
            gload16(gp, &sA[buf][(wave * 32 + i * 4) * 64]);
        }
    };
    // --- B DMA: identity copy, wave w does bytes [(w*8+i)*1KB, +1KB)
    auto issue_B = [&](int tl) {
        const uint16_t* tb = Bpk + (size_t)tid2glob(tl) * 8192;
#pragma unroll
        for (int i = 0; i < 8; ++i) {
            const uint16_t* gp = tb + (wave * 8 + i) * 512 + lane * 8;
            gload16(gp, &sB[(wave * 8 + i) * 512]);
        }
    };

    // Precompute per-thread A fragment byte offsets: (rt, ks) -> two b128 addrs
    int aoff[2][2][2];
#pragma unroll
    for (int rt = 0; rt < 2; ++rt) {
#pragma unroll
        for (int ks = 0; ks < 2; ++ks) {
            int row = wave * 32 + rt * 16 + (lane & 15);
            int c0 = 8 * ks + 2 * kq;
            aoff[rt][ks][0] = row * 256 + ((c0) ^ (row & 7)) * 16;
            aoff[rt][ks][1] = row * 256 + ((c0 + 1) ^ (row & 7)) * 16;
        }
    }

    auto compute_tile = [&](const float* sAb) {
#pragma unroll
        for (int ks = 0; ks < 2; ++ks) {
            const int bko = (ks * 4 + kq) * 512;
#pragma unroll
            for (int rt = 0; rt < 2; ++rt) {
                f32x4 a0 = *(const f32x4*)((const char*)sAb + aoff[rt][ks][0]);
                f32x4 a1 = *(const f32x4*)((const char*)sAb + aoff[rt][ks][1]);
                u32x2 h0, l0, h1, l1;
                split4_pk(a0, h0, l0);
                split4_pk(a1, h1, l1);
                u32x4 H, L;
                H[0] = h0[0]; H[1] = h0[1]; H[2] = h1[0]; H[3] = h1[1];
                L[0] = l0[0]; L[1] = l0[1]; L[2] = l1[0]; L[3] = l1[1];
                bfrag8 ah = *(bfrag8*)&H;
                bfrag8 al = *(bfrag8*)&L;
#pragma unroll
                for (int ct = 0; ct < 4; ++ct) {
                    int col = ct * 16 + (lane & 15);
                    bfrag8 bh = *(const bfrag8*)&sB[bko + col * 8];
                    bfrag8 bl = *(const bfrag8*)&sB[4096 + bko + col * 8];
                    acc[rt][ct] = __builtin_amdgcn_mfma_f32_16x16x32_bf16(ah, bh, acc[rt][ct], 0, 0, 0);
                    acc[rt][ct] = __builtin_amdgcn_mfma_f32_16x16x32_bf16(al, bh, acc[rt][ct], 0, 0, 0);
                    acc[rt][ct] = __builtin_amdgcn_mfma_f32_16x16x32_bf16(ah, bl, acc[rt][ct], 0, 0, 0);
                }
            }
        }
    };

    // prologue
    issue_A(0, 0);
    issue_B(0);
    int cur = 0;
    for (int tl = 0; tl < ktiles; ++tl) {
        vm_sync();                                   // A(t)+B(t) DMA complete
        if (tl + 1 < ktiles) issue_A(tl + 1, cur ^ 1);
        compute_tile(sA[cur]);
        lds_sync();                                  // all waves done reading sB
        if (tl + 1 < ktiles) issue_B(tl + 1);
        cur ^= 1;
    }

    // epilogue: C layout (m89-verified): col = lane&15, row = (lane>>4)*4 + reg
    float* pout = partial + (size_t)kc * ((size_t)NN * 64);
    const int ocol = lane & 15;
#pragma unroll
    for (int rt = 0; rt < 2; ++rt) {
        const int orow = rb * 64 + wave * 32 + rt * 16 + (lane >> 4) * 4;
#pragma unroll
        for (int ct = 0; ct < 4; ++ct) {
#pragma unroll
            for (int r = 0; r < 4; ++r) {
                pout[(size_t)(orow + r) * 64 + ct * 16 + ocol] = acc[rt][ct][r];
            }
        }
    }
}

// ---------------------------------------------------------------------------
// Fused: m = sum(partials); GRUCell(m, x); relu; write fp32 output.
__global__ void __launch_bounds__(256, 4) gru_kernel(
    const float* __restrict__ partial, int ksplit,
    const float* __restrict__ Xin,
    const float* __restrict__ wtih,  // [64][192]
    const float* __restrict__ wthh,  // [64][192]
    const float* __restrict__ bih,
    const float* __restrict__ bhh,
    float* __restrict__ hout) {
    __shared__ __align__(16) float sM[32 * 64];
    __shared__ __align__(16) float sX[32 * 64];
    const int t = threadIdx.x;
    const int nb = blockIdx.x * 32;
    {
        size_t g0 = (size_t)nb * 64 + (size_t)t * 8;
        f32x4 s0, s1;
        {
            const f32x4* p0 = (const f32x4*)(partial + g0);
            s0 = p0[0]; s1 = p0[1];
        }
        for (int p = 1; p < ksplit; p++) {
            const f32x4* pp = (const f32x4*)(partial + (size_t)p * ((size_t)NN * 64) + g0);
            f32x4 a = pp[0], b = pp[1];
#pragma unroll
            for (int q = 0; q < 4; q++) { s0[q] += a[q]; s1[q] += b[q]; }
        }
        *(f32x4*)&sM[t * 8] = s0;
        *(f32x4*)&sM[t * 8 + 4] = s1;
        const f32x4* px = (const f32x4*)(Xin + g0);
        *(f32x4*)&sX[t * 8] = px[0];
        *(f32x4*)&sX[t * 8 + 4] = px[1];
    }
    __syncthreads();
    const int wave = t >> 6, lane = t & 63;
    const int nodebase = wave * 8;
    float a_ir[8], a_iz[8], a_in[8], a_hr[8], a_hz[8], a_hn[8];
#pragma unroll
    for (int n = 0; n < 8; n++) {
        a_ir[n] = 0.f; a_iz[n] = 0.f; a_in[n] = 0.f;
        a_hr[n] = 0.f; a_hz[n] = 0.f; a_hn[n] = 0.f;
    }
    for (int k = 0; k < 64; k++) {
        float w0 = wtih[k * 192 + lane];
        float w1 = wtih[k * 192 + 64 + lane];
        float w2 = wtih[k * 192 + 128 + lane];
        float w3 = wthh[k * 192 + lane];
        float w4 = wthh[k * 192 + 64 + lane];
        float w5 = wthh[k * 192 + 128 + lane];
#pragma unroll
        for (int n = 0; n < 8; n++) {
            float mv = sM[(nodebase + n) * 64 + k];
            float xv = sX[(nodebase + n) * 64 + k];
            a_ir[n] += w0 * mv; a_iz[n] += w1 * mv; a_in[n] += w2 * mv;
            a_hr[n] += w3 * xv; a_hz[n] += w4 * xv; a_hn[n] += w5 * xv;
        }
    }
    const float b0 = bih[lane], b1 = bih[64 + lane], b2 = bih[128 + lane];
    const float b3 = bhh[lane], b4 = bhh[64 + lane], b5 = bhh[128 + lane];
#pragma unroll
    for (int n = 0; n < 8; n++) {
        float ir = a_ir[n] + b0, iz = a_iz[n] + b1, inn = a_in[n] + b2;
        float hr = a_hr[n] + b3, hz = a_hz[n] + b4, hn = a_hn[n] + b5;
        float r = 1.f / (1.f + __expf(-(ir + hr)));
        float z = 1.f / (1.f + __expf(-(iz + hz)));
        float nt = tanhf(inn + r * hn);
        float xv = sX[(nodebase + n) * 64 + lane];
        float o = (1.f - z) * nt + z * xv;
        o = fmaxf(o, 0.f);
        size_t oi = (size_t)(nb + nodebase + n) * 64 + lane;
        hout[oi] = o;
    }
}

// ---------------------------------------------------------------------------
extern "C" void kernel_launch(void* const* d_in, const int* in_sizes, int n_in,
                              void* d_out, int out_size, void* d_ws, size_t ws_size,
                              hipStream_t stream) {
    const float* x    = (const float*)d_in[0];
    const float* adj  = (const float*)d_in[1];
    const float* W1   = (const float*)d_in[2];
    const float* wih1 = (const float*)d_in[3];
    const float* whh1 = (const float*)d_in[4];
    const float* bih1 = (const float*)d_in[5];
    const float* bhh1 = (const float*)d_in[6];
    const float* W2   = (const float*)d_in[7];
    const float* wih2 = (const float*)d_in[8];
    const float* whh2 = (const float*)d_in[9];
    const float* bih2 = (const float*)d_in[10];
    const float* bhh2 = (const float*)d_in[11];
    float* out = (float*)d_out;   // reference output dtype is float32

    char* p = (char*)d_ws;
    float* wtih1 = (float*)p; p += (size_t)192 * 64 * 4;
    float* wthh1 = (float*)p; p += (size_t)192 * 64 * 4;
    float* wtih2 = (float*)p; p += (size_t)192 * 64 * 4;
    float* wthh2 = (float*)p; p += (size_t)192 * 64 * 4;
    float* h     = (float*)p; p += (size_t)NN * 64 * 4;
    uint16_t* Bpk = (uint16_t*)p; p += (size_t)NN * 64 * 2 * 2;  // hi+lo packed
    float* partial = (float*)p;
    size_t used = (size_t)(p - (char*)d_ws);
    size_t unit = (size_t)NN * 64 * 4;

    int ksplit = 1;
    const int opts[3] = {4, 2, 1};
    for (int i = 0; i < 3; i++) {
        if (used + (size_t)opts[i] * unit <= ws_size) { ksplit = opts[i]; break; }
    }
    int ktiles = 192 / ksplit;

    wt4_kernel<<<dim3(48, 4), 256, 0, stream>>>(wih1, whh1, wih2, whh2,
                                                wtih1, wthh1, wtih2, wthh2);

    // layer 1 (forward K order)
    xw_kernel<<<192, 256, 0, stream>>>(x, W1, Bpk);
    spmm_kernel<<<dim3(192, ksplit), 128, 0, stream>>>(adj, Bpk, partial, ktiles, 0);
    gru_kernel<<<384, 256, 0, stream>>>(partial, ksplit, x, wtih1, wthh1, bih1, bhh1, h);
    // layer 2 (reverse K order — boustrophedon: reuse adj tail still in L3)
    xw_kernel<<<192, 256, 0, stream>>>(h, W2, Bpk);
    spmm_kernel<<<dim3(192, ksplit), 128, 0, stream>>>(adj, Bpk, partial, ktiles, 1);
    gru_kernel<<<384, 256, 0, stream>>>(partial, ksplit, h, wtih2, wthh2, bih2, bhh2, out);
}